// Round 7
// baseline (2737.124 us; speedup 1.0000x reference)
//
#include <hip/hip_runtime.h>
#include <hip/hip_bf16.h>
#include <cstdint>

// ---------------------------------------------------------------------------
// Decoder LSTM (teacher-forced), MI355X.
//   1. cvt_bf16: W_out, W_ih, W_hh fp32 -> bf16 (ws)
//   2. gather_embed: X[t*16+b] = bf16(relu(emb[tok])) (t-major) + NaN-fill Hs
//   3. gemm_bt: G0 = X @ W_ih^T + b_ih + b_hh  (fp32, t-major rows)
//   4. lstm_rec: SAME-XCD recurrence. 121 blocks launched; only bid%8==0
//      work (round-robin dispatch -> all 16 workers on XCD 0, sharing ONE
//      L2). h exchange: sc0-sc1 write-through stores + sc0 loads served by
//      the shared L2 (~200cy visibility). Sentinel data-as-flag (bf16 NaN
//      0x7FC0). Escalation: chunks stale >=8 polls retry with sc0 sc1
//      (IF-coherent) -> correct on ANY block->XCD mapping.
//      (R2/R4 evidence: agent-atomic spin loads serve from the reader's own
//      stale XCD L2 -> progress only on eviction, 11-14 us/step. R0's
//      per-step buffer_inv cost ~5 us/step. Same-L2 avoids both.)
//   5. gemm_bt (tmajor epilogue): logits = Hs @ W_out^T + b_out -> d_out
// ---------------------------------------------------------------------------

#define V_ 32000
#define H_ 512
#define B_ 16
#define T_ 128

typedef __attribute__((ext_vector_type(8))) short s16x8;
typedef __attribute__((ext_vector_type(4))) float f32x4;

typedef unsigned int __attribute__((address_space(1))) as1_u32;
typedef unsigned int __attribute__((address_space(3))) as3_u32;

#define MFMA16 __builtin_amdgcn_mfma_f32_16x16x32_bf16

__device__ __forceinline__ void async_cp16(const void* g, void* l) {
  __builtin_amdgcn_global_load_lds((const as1_u32*)g, (as3_u32*)l, 16, 0, 0);
}

__device__ __forceinline__ short f2bf(float f) {
  union { float f; unsigned u; } v; v.f = f;
  unsigned r = v.u + 0x7fffu + ((v.u >> 16) & 1u);   // RNE, inputs finite
  return (short)(r >> 16);
}

// L1-bypass load, served by this XCD's L2 (fast same-XCD visibility).
__device__ __forceinline__ void load16_sc0(s16x8& d, const short* p) {
  asm volatile("global_load_dwordx4 %0, %1, off sc0" : "=&v"(d) : "v"(p));
}
// L1+L2-bypass load, served at the IF coherence point (cross-XCD truth).
__device__ __forceinline__ void load16_sc01(s16x8& d, const short* p) {
  asm volatile("global_load_dwordx4 %0, %1, off sc0 sc1" : "=&v"(d) : "v"(p));
}
// Write-through store: updates local L2 AND propagates to IF.
__device__ __forceinline__ void store8_wt(short* p, unsigned long long v) {
  asm volatile("global_store_dwordx2 %0, %1, off sc0 sc1" :: "v"(p), "v"(v) : "memory");
}

// ---------------------------------------------------------------------------
__global__ void cvt_bf16(const float* __restrict__ in, short* __restrict__ out, int n4) {
  int i = blockIdx.x * blockDim.x + threadIdx.x;
  if (i >= n4) return;
  float4 v = ((const float4*)in)[i];
  short4 o;
  o.x = f2bf(v.x); o.y = f2bf(v.y); o.z = f2bf(v.z); o.w = f2bf(v.w);
  ((short4*)out)[i] = o;
}

// grid 2048 blocks (one per (b,t)), 128 threads. X stored T-MAJOR: row t*16+b.
// Also NaN-fills Hs row m (sentinel for lstm_rec's data-spin); write-through
// so HBM/IF holds the sentinel before lstm_rec starts.
__global__ void gather_embed(const float* __restrict__ emb, const int* __restrict__ tgt,
                             short* __restrict__ X, short* __restrict__ Hs) {
  int m = blockIdx.x;
  int b = m >> 7, t = m & 127;
  int tok = (t == 0) ? 1 : tgt[b * T_ + t - 1];       // BOS = 1
  int k = threadIdx.x * 4;
  float4 v = *(const float4*)&emb[(size_t)tok * H_ + k];
  short4 o;
  o.x = f2bf(fmaxf(v.x, 0.f)); o.y = f2bf(fmaxf(v.y, 0.f));
  o.z = f2bf(fmaxf(v.z, 0.f)); o.w = f2bf(fmaxf(v.w, 0.f));
  *(short4*)&X[((size_t)t * 16 + b) * H_ + k] = o;
  store8_wt(&Hs[(size_t)m * H_ + threadIdx.x * 4], 0x7FC07FC07FC07FC0ull);
}

// ---------------------------------------------------------------------------
// C = A(MxK bf16) @ B(NxK bf16)^T + bias ; 128x128 tile, BK=64, 4 waves,
// XOR-swizzled LDS chunks -> conflict-free ds_read_b128.
// tmajor: A rows are t*16+b, output rows must be b*T+t (logits GEMM).
__global__ __launch_bounds__(256, 2) void gemm_bt(
    const short* __restrict__ A, const short* __restrict__ B,
    const float* __restrict__ bias0, const float* __restrict__ bias1,
    float* __restrict__ out, int M, int N, int K, int ldo, int tmajor)
{
  __shared__ short As[1024 * 8];
  __shared__ short Bs[1024 * 8];
  const int tid = threadIdx.x;
  const int wave = tid >> 6, lane = tid & 63;
  const int row0 = blockIdx.y * 128, col0 = blockIdx.x * 128;
  const int m_in = lane & 15, quad = lane >> 4;
  const int wm = (wave >> 1) * 64, wn = (wave & 1) * 64;
  f32x4 acc[4][4] = {};
  for (int kt = 0; kt < K; kt += 64) {
    for (int i = 0; i < 4; ++i) {
      int s = (i * 4 + wave) * 64 + lane;
      int r = s >> 3, cs = s & 7, cd = cs ^ (r & 7);
      async_cp16(A + ((size_t)(row0 + r) * K + kt + cd * 8), &As[s * 8]);
      async_cp16(B + ((size_t)(col0 + r) * K + kt + cd * 8), &Bs[s * 8]);
    }
    __syncthreads();
    for (int kk = 0; kk < 2; ++kk) {
      s16x8 af[4], bfr[4];
      int c = kk * 4 + quad;
      for (int i = 0; i < 4; ++i) {
        int ra = wm + i * 16 + m_in;
        af[i] = *(const s16x8*)&As[(ra * 8 + (c ^ (ra & 7))) * 8];
        int rb = wn + i * 16 + m_in;
        bfr[i] = *(const s16x8*)&Bs[(rb * 8 + (c ^ (rb & 7))) * 8];
      }
      for (int i = 0; i < 4; ++i)
        for (int j = 0; j < 4; ++j)
          acc[i][j] = MFMA16(af[i], bfr[j], acc[i][j], 0, 0, 0);
    }
    __syncthreads();
  }
  for (int j = 0; j < 4; ++j) {
    int n = col0 + wn + j * 16 + m_in;
    float bs = bias0[n] + (bias1 ? bias1[n] : 0.f);
    for (int i = 0; i < 4; ++i) {
      int mrow = row0 + wm + i * 16 + quad * 4;      // D: col=lane&15, row=quad*4+reg
      f32x4 a = acc[i][j];
      for (int p = 0; p < 4; ++p) {
        int mr = mrow + p;
        int orow = tmajor ? ((mr & 15) * T_ + (mr >> 4)) : mr;
        out[(size_t)orow * ldo + n] = a[p] + bs;
      }
    }
  }
}

// ---------------------------------------------------------------------------
// Recurrence: 121 blocks launched, only bid%8==0 work (16 workers, all on
// XCD 0 under round-robin dispatch; 1 block/CU via 141KB LDS -> co-resident).
// Worker S owns hidden slice [S*32, S*32+32); wave w owns units S*32+w*4..+4
// for ALL 4 gates. W_hh slice in LDS (swizzled). Per step:
//   batch sc0-load 16 h chunks (shared-L2) -> vmcnt(0)+sched_barrier ->
//   sentinel-spin (escalate stale chunks to sc0-sc1/IF after 8 polls) ->
//   2 MFMA chains -> in-wave LDS gate exchange -> fp32 gate math ->
//   pack h -> 8B write-through store -> G0 prefetch.
__global__ __launch_bounds__(512, 1) void lstm_rec(
    const float* __restrict__ G0,    // [2048][2048] fp32, rows t-major
    const short* __restrict__ Whh,   // [2048][512] bf16
    const float* __restrict__ h0, const float* __restrict__ c0,
    short* __restrict__ Hs,          // [2048][512] bf16, t-major, NaN-filled
    float* __restrict__ hcf)         // hf[B*H] then cf[B*H]
{
  __shared__ short Wl[8192 * 8];     // 128 rows x 64 chunks x 16B = 128KB
  __shared__ float gw_s[8 * 320];    // per-wave 16x20 fp32 scratch
  const int bid = blockIdx.x;
  if (bid & 7) return;               // keep only XCD-0 blocks (round-robin)
  const int S = bid >> 3;
  const int tid = threadIdx.x, wave = tid >> 6, lane = tid & 63;
  const int nin = lane & 15, quad = lane >> 4;
  const int g = nin >> 2, j = nin & 3;               // gate-major B-row mapping
  const int r = g * 32 + wave * 4 + j;               // local W row (B operand)

  // Stage W slice. Local row rr -> global unit (rr/32)*512 + S*32 + (rr%32).
  for (int i = tid; i < 8192; i += 512) {
    int rr = i >> 6, cs = i & 63, cd = cs ^ (rr & 7);
    int u = (rr >> 5) * 512 + S * 32 + (rr & 31);
    *(int4*)&Wl[i * 8] = *(const int4*)&Whh[(size_t)u * H_ + cd * 8];
  }
  const int goff = S * 32 + wave * 4 + quad;         // this lane's unit (reader view)
  float c_reg = c0[nin * 512 + goff];
  float* gw = gw_s + wave * 320;
  // G0 prefetch for tt=0 (row = 0*16 + nin)
  float gx0 = G0[(size_t)nin * 2048 + goff];
  float gx1 = G0[(size_t)nin * 2048 + 512 + goff];
  float gx2 = G0[(size_t)nin * 2048 + 1024 + goff];
  float gx3 = G0[(size_t)nin * 2048 + 1536 + goff];
  __syncthreads();                                   // Wl staged

  for (int tt = 0; tt < T_; ++tt) {
    // ---- acquire h(tt-1) into hv[16] ----
    s16x8 hv[16];
    if (tt == 0) {
#pragma unroll
      for (int ks = 0; ks < 16; ++ks) {
        const float* hp = h0 + nin * 512 + ks * 32 + quad * 8;
        float4 v0 = *(const float4*)hp, v1 = *(const float4*)(hp + 4);
        s16x8 af;
        af[0] = f2bf(v0.x); af[1] = f2bf(v0.y); af[2] = f2bf(v0.z); af[3] = f2bf(v0.w);
        af[4] = f2bf(v1.x); af[5] = f2bf(v1.y); af[6] = f2bf(v1.z); af[7] = f2bf(v1.w);
        hv[ks] = af;
      }
    } else {
      const short* hrow = Hs + ((size_t)(tt - 1) * 16 + nin) * 512 + quad * 8;
#pragma unroll
      for (int ks = 0; ks < 16; ++ks)
        load16_sc0(hv[ks], hrow + ks * 32);          // batch-issued, shared L2
      asm volatile("s_waitcnt vmcnt(0)" ::: "memory");
      __builtin_amdgcn_sched_barrier(0);             // rule #18: pin consumers
      int spins = 0;
      while (true) {                                 // sentinel data-spin
        unsigned stale = 0;
#pragma unroll
        for (int ks = 0; ks < 16; ++ks)
          if (((unsigned short)hv[ks][0] == 0x7FC0u) ||
              ((unsigned short)hv[ks][4] == 0x7FC0u))
            stale |= 1u << ks;
        if (stale == 0) break;
        __builtin_amdgcn_s_sleep(1);
        ++spins;
        if (spins < 8) {                             // fast path: shared L2
#pragma unroll
          for (int ks = 0; ks < 16; ++ks)
            if (stale & (1u << ks)) load16_sc0(hv[ks], hrow + ks * 32);
        } else {                                     // escalation: IF truth
#pragma unroll
          for (int ks = 0; ks < 16; ++ks)
            if (stale & (1u << ks)) load16_sc01(hv[ks], hrow + ks * 32);
        }
        asm volatile("s_waitcnt vmcnt(0)" ::: "memory");
        __builtin_amdgcn_sched_barrier(0);
      }
    }
    // ---- MFMA: 16 batches x 16 (gate,unit) rows over K=512 ----
    f32x4 a0 = {}, a1 = {};
#pragma unroll
    for (int ks = 0; ks < 16; ++ks) {
      int c = ks * 4 + quad;
      s16x8 bw = *(const s16x8*)&Wl[(r * 64 + (c ^ (r & 7))) * 8];
      if (ks < 8) a0 = MFMA16(hv[ks], bw, a0, 0, 0, 0);
      else        a1 = MFMA16(hv[ks], bw, a1, 0, 0, 0);
    }
    f32x4 acc = a0 + a1;
    // in-wave gate exchange (no barrier; lgkmcnt orders ds ops per-wave)
    *(f32x4*)&gw[nin * 20 + quad * 4] = acc;         // [col=(g,j)][batch]
    float pi = gw[(0 * 4 + quad) * 20 + nin];
    float pf = gw[(1 * 4 + quad) * 20 + nin];
    float pg = gw[(2 * 4 + quad) * 20 + nin];
    float po = gw[(3 * 4 + quad) * 20 + nin];
    float xi = gx0 + pi, xf = gx1 + pf, xg = gx2 + pg, xo = gx3 + po;
    float si = 1.f / (1.f + __expf(-xi));
    float sf = 1.f / (1.f + __expf(-xf));
    float so = 1.f / (1.f + __expf(-xo));
    c_reg = sf * c_reg + si * tanhf(xg);
    float hn = so * tanhf(c_reg);
    // pack this wave's 4 units for batch nin, 8B write-through store
    int v0 = (int)(unsigned short)f2bf(hn);
    int v1 = __shfl(v0, (lane & 15) + 16);
    int v2 = __shfl(v0, (lane & 15) + 32);
    int v3 = __shfl(v0, (lane & 15) + 48);
    if (lane < 16) {
      unsigned long long pk = (unsigned long long)(unsigned)v0
                            | ((unsigned long long)(unsigned)v1 << 16)
                            | ((unsigned long long)(unsigned)v2 << 32)
                            | ((unsigned long long)(unsigned)v3 << 48);
      store8_wt(&Hs[((size_t)tt * 16 + nin) * 512 + S * 32 + wave * 4], pk);
    }
    if (tt == T_ - 1) {
      hcf[nin * 512 + goff] = hn;
      hcf[B_ * H_ + nin * 512 + goff] = c_reg;
    }
    if (tt < T_ - 1) {                               // prefetch next G0 row;
      const float* gp = G0 + ((size_t)(tt + 1) * 16 + nin) * 2048 + goff;
      gx0 = gp[0]; gx1 = gp[512]; gx2 = gp[1024]; gx3 = gp[1536];
    }                                                // overlaps next data-spin
  }
}

// ---------------------------------------------------------------------------
extern "C" void kernel_launch(void* const* d_in, const int* in_sizes, int n_in,
                              void* d_out, int out_size, void* d_ws, size_t ws_size,
                              hipStream_t stream) {
  (void)in_sizes; (void)n_in; (void)out_size;
  const float* h0   = (const float*)d_in[1];
  const float* c0   = (const float*)d_in[2];
  const int*   tgt  = (const int*)d_in[3];
  const float* emb  = (const float*)d_in[4];
  const float* Wih  = (const float*)d_in[5];
  const float* Whh  = (const float*)d_in[6];
  const float* bih  = (const float*)d_in[7];
  const float* bhh  = (const float*)d_in[8];
  const float* Wout = (const float*)d_in[9];
  const float* bout = (const float*)d_in[10];
  float* out = (float*)d_out;

  char* ws = (char*)d_ws;
  short* wsWout = (short*)(ws);                 // 32,768,000 B
  short* wsWih  = (short*)(ws + 32768000);      //  2,097,152 B
  short* wsWhh  = (short*)(ws + 34865152);      //  2,097,152 B
  short* wsX    = (short*)(ws + 36962304);      //  2,097,152 B
  short* wsHs   = (short*)(ws + 39059456);      //  2,097,152 B
  const size_t NEED = 41160704ull + 16777216ull;
  // G0 in ws if it fits; else d_out scratch (safe: lstm_rec finishes reading
  // G0 before the logits gemm starts overwriting out — same stream).
  float* G0 = (ws_size >= NEED) ? (float*)(ws + 41160704) : out;

  cvt_bf16<<<16000, 256, 0, stream>>>(Wout, wsWout, 4096000);
  cvt_bf16<<<1024, 256, 0, stream>>>(Wih, wsWih, 262144);
  cvt_bf16<<<1024, 256, 0, stream>>>(Whh, wsWhh, 262144);
  gather_embed<<<2048, 128, 0, stream>>>(emb, tgt, wsX, wsHs);
  gemm_bt<<<dim3(16, 16), 256, 0, stream>>>(wsX, wsWih, bih, bhh, G0,
                                            2048, 2048, 512, 2048, 0);
  float* hcf = out + (size_t)B_ * T_ * V_;
  lstm_rec<<<121, 512, 0, stream>>>(G0, wsWhh, h0, c0, wsHs, hcf);
  gemm_bt<<<dim3(250, 16), 256, 0, stream>>>(wsHs, wsWout, bout, nullptr, out,
                                             2048, 32000, 512, 32000, 1);
}

// Round 10
// 1213.141 us; speedup vs baseline: 2.2562x; 2.2562x over previous
//
#include <hip/hip_runtime.h>
#include <hip/hip_bf16.h>
#include <cstdint>

// ---------------------------------------------------------------------------
// Decoder LSTM (teacher-forced), MI355X.
//   1. cvt_bf16: W_out, W_ih, W_hh fp32 -> bf16 (ws)
//   2. gather_embed: X[t*16+b] = bf16(relu(emb[tok])) (t-major), zero flags
//   3. gemm_bt: G0 = X @ W_ih^T + b_ih + b_hh  (fp32, t-major rows)
//   4. rec_logits (fused, 121 blocks x 512 thr, 1 block/CU via 156KB LDS):
//      - bid%8==0 (16 blocks -> XCD 0 under round-robin): R0's PROVEN
//        fence-based recurrence (flags[t] = #blocks done step t,
//        __threadfence release/acquire). ~5 us/step measured in the 947us
//        session. All spin/lock-free variants measured 11-18 us/step
//        (R2/R4/R7): sc0/sc1+sentinel tricks can't beat buffer_inv.
//      - bid%8!=0 (105 workers on XCDs 1-7): logits tiles gated per
//        8-step band on flags[ty*8+7]>=16, throttled polls (s_sleep),
//        per-band threadfence acquire. Worker fences never touch XCD 0's
//        L2 (R1's poisoning), polls are read-only + slow (R1's contention).
//   5. fallback (ws too small): same kernel workers-off + separate gemm_bt.
// ---------------------------------------------------------------------------

#define V_ 32000
#define H_ 512
#define B_ 16
#define T_ 128

typedef __attribute__((ext_vector_type(8))) short s16x8;
typedef __attribute__((ext_vector_type(4))) float f32x4;

typedef unsigned int __attribute__((address_space(1))) as1_u32;
typedef unsigned int __attribute__((address_space(3))) as3_u32;

#define MFMA16 __builtin_amdgcn_mfma_f32_16x16x32_bf16

__device__ __forceinline__ void async_cp16(const void* g, void* l) {
  __builtin_amdgcn_global_load_lds((const as1_u32*)g, (as3_u32*)l, 16, 0, 0);
}

__device__ __forceinline__ short f2bf(float f) {
  union { float f; unsigned u; } v; v.f = f;
  unsigned r = v.u + 0x7fffu + ((v.u >> 16) & 1u);   // RNE, inputs finite
  return (short)(r >> 16);
}

// ---------------------------------------------------------------------------
__global__ void cvt_bf16(const float* __restrict__ in, short* __restrict__ out, int n4) {
  int i = blockIdx.x * blockDim.x + threadIdx.x;
  if (i >= n4) return;
  float4 v = ((const float4*)in)[i];
  short4 o;
  o.x = f2bf(v.x); o.y = f2bf(v.y); o.z = f2bf(v.z); o.w = f2bf(v.w);
  ((short4*)out)[i] = o;
}

// grid 2048 blocks (one per (b,t)), 128 threads. X stored T-MAJOR: row t*16+b.
// Zeroes the 128 step flags (re-poisoned every launch, before rec_logits).
__global__ void gather_embed(const float* __restrict__ emb, const int* __restrict__ tgt,
                             short* __restrict__ X, int* __restrict__ flags) {
  int m = blockIdx.x;
  int b = m >> 7, t = m & 127;
  int tok = (t == 0) ? 1 : tgt[b * T_ + t - 1];       // BOS = 1
  int k = threadIdx.x * 4;
  float4 v = *(const float4*)&emb[(size_t)tok * H_ + k];
  short4 o;
  o.x = f2bf(fmaxf(v.x, 0.f)); o.y = f2bf(fmaxf(v.y, 0.f));
  o.z = f2bf(fmaxf(v.z, 0.f)); o.w = f2bf(fmaxf(v.w, 0.f));
  *(short4*)&X[((size_t)t * 16 + b) * H_ + k] = o;
  if (m == 0) flags[threadIdx.x] = 0;                 // 128 step flags
}

// ---------------------------------------------------------------------------
// C = A(MxK bf16) @ B(NxK bf16)^T + bias ; 128x128 tile, BK=64, 4 waves,
// XOR-swizzled LDS chunks -> conflict-free ds_read_b128.
// tmajor: A rows are t*16+b, output rows must be b*T+t.
__global__ __launch_bounds__(256, 2) void gemm_bt(
    const short* __restrict__ A, const short* __restrict__ B,
    const float* __restrict__ bias0, const float* __restrict__ bias1,
    float* __restrict__ out, int M, int N, int K, int ldo, int tmajor)
{
  __shared__ short As[1024 * 8];
  __shared__ short Bs[1024 * 8];
  const int tid = threadIdx.x;
  const int wave = tid >> 6, lane = tid & 63;
  const int row0 = blockIdx.y * 128, col0 = blockIdx.x * 128;
  const int m_in = lane & 15, quad = lane >> 4;
  const int wm = (wave >> 1) * 64, wn = (wave & 1) * 64;
  f32x4 acc[4][4] = {};
  for (int kt = 0; kt < K; kt += 64) {
    for (int i = 0; i < 4; ++i) {
      int s = (i * 4 + wave) * 64 + lane;
      int r = s >> 3, cs = s & 7, cd = cs ^ (r & 7);
      async_cp16(A + ((size_t)(row0 + r) * K + kt + cd * 8), &As[s * 8]);
      async_cp16(B + ((size_t)(col0 + r) * K + kt + cd * 8), &Bs[s * 8]);
    }
    __syncthreads();
    for (int kk = 0; kk < 2; ++kk) {
      s16x8 af[4], bfr[4];
      int c = kk * 4 + quad;
      for (int i = 0; i < 4; ++i) {
        int ra = wm + i * 16 + m_in;
        af[i] = *(const s16x8*)&As[(ra * 8 + (c ^ (ra & 7))) * 8];
        int rb = wn + i * 16 + m_in;
        bfr[i] = *(const s16x8*)&Bs[(rb * 8 + (c ^ (rb & 7))) * 8];
      }
      for (int i = 0; i < 4; ++i)
        for (int j = 0; j < 4; ++j)
          acc[i][j] = MFMA16(af[i], bfr[j], acc[i][j], 0, 0, 0);
    }
    __syncthreads();
  }
  for (int j = 0; j < 4; ++j) {
    int n = col0 + wn + j * 16 + m_in;
    float bs = bias0[n] + (bias1 ? bias1[n] : 0.f);
    for (int i = 0; i < 4; ++i) {
      int mrow = row0 + wm + i * 16 + quad * 4;      // D: col=lane&15, row=quad*4+reg
      f32x4 a = acc[i][j];
      for (int p = 0; p < 4; ++p) {
        int mr = mrow + p;
        int orow = tmajor ? ((mr & 15) * T_ + (mr >> 4)) : mr;
        out[(size_t)orow * ldo + n] = a[p] + bs;
      }
    }
  }
}

// ---------------------------------------------------------------------------
// Fused recurrence + logits. 121 blocks x 512 threads; 156KB LDS -> 1/CU,
// all co-resident (121 < 256 CUs) -> gating cannot deadlock.
__global__ __launch_bounds__(512, 1) void rec_logits(
    const float* __restrict__ G0,    // [2048][2048] fp32, rows t-major
    const short* __restrict__ Whh,   // [2048][512] bf16
    const float* __restrict__ h0, const float* __restrict__ c0,
    short* __restrict__ Hs,          // [2048][512] bf16, rows t-major
    const short* __restrict__ Wout,  // [32000][512] bf16
    const float* __restrict__ bout,
    int* flags,                      // flags[t] = #blocks done step t
    float* __restrict__ out,         // logits, row b*T+t
    float* __restrict__ hcf,         // hf[B*H] then cf[B*H]
    int workers_on)
{
  __shared__ char smem[156160];      // rec: Wl 128K | hl 16K | gl 8.5K ; wrk: As/Bs 32K
  const int bid = blockIdx.x;
  const int tid = threadIdx.x, wave = tid >> 6, lane = tid & 63;

  if ((bid & 7) == 0) {
    // ---------------- recurrence (R0 protocol, verbatim; t-major Hs/G0) ----
    short* Wl = (short*)smem;                       // 128 rows x 64 chunks x 16B
    short* hl = (short*)(smem + 131072);            // 16 rows x 64 chunks x 16B
    float* gl = (float*)(smem + 147456);            // [128][17] fp32
    const int S = bid >> 3;
    const int nin = lane & 15, quad = lane >> 4;
    // Stage W slice. Local row r -> global unit (r/32)*512 + S*32 + (r%32).
    for (int i = tid; i < 8192; i += 512) {
      int r = i >> 6, cs = i & 63, cd = cs ^ (r & 7);
      int u = (r >> 5) * 512 + S * 32 + (r & 31);
      *(int4*)&Wl[i * 8] = *(const int4*)&Whh[(size_t)u * H_ + cd * 8];
    }
    const int batch = tid >> 5, hid = tid & 31;
    float c_reg = c0[batch * H_ + S * 32 + hid];
    __syncthreads();

    for (int tt = 0; tt < T_; ++tt) {
      if (tt > 0) {
        if (tid == 0) {
          while (__hip_atomic_load(&flags[tt - 1], __ATOMIC_RELAXED, __HIP_MEMORY_SCOPE_AGENT) < 16) {}
          __threadfence();           // acquire: invalidate before reading Hs
        }
        __syncthreads();
      }
      // Stage h (16 batches x 512) into hl, swizzled.
      for (int i = tid; i < 1024; i += 512) {
        int m = i >> 6, cs = i & 63, cd = cs ^ (m & 7);
        if (tt == 0) {
          const float* hp = &h0[m * H_ + cd * 8];
          float4 v0 = *(const float4*)hp, v1 = *(const float4*)(hp + 4);
          s16x8 o;
          o[0] = f2bf(v0.x); o[1] = f2bf(v0.y); o[2] = f2bf(v0.z); o[3] = f2bf(v0.w);
          o[4] = f2bf(v1.x); o[5] = f2bf(v1.y); o[6] = f2bf(v1.z); o[7] = f2bf(v1.w);
          *(s16x8*)&hl[i * 8] = o;
        } else {
          *(int4*)&hl[i * 8] = *(const int4*)&Hs[((size_t)(tt - 1) * 16 + m) * H_ + cd * 8];
        }
      }
      __syncthreads();
      // MFMA: wave w computes units [w*16, w*16+16) x 16 batches over K=512.
      {
        f32x4 acc = {};
        int r = wave * 16 + nin;
        for (int ks = 0; ks < 16; ++ks) {
          int c = ks * 4 + quad;
          s16x8 af = *(const s16x8*)&hl[(nin * 64 + (c ^ (nin & 7))) * 8];
          s16x8 bf = *(const s16x8*)&Wl[(r * 64 + (c ^ (r & 7))) * 8];
          acc = MFMA16(af, bf, acc, 0, 0, 0);
        }
        int u = wave * 16 + nin;
        for (int p = 0; p < 4; ++p)
          gl[u * 17 + quad * 4 + p] = acc[p];        // D: col=unit, row=batch
      }
      __syncthreads();
      // Pointwise gates (fp32), one (batch, hid) per thread.
      {
        size_t gbase = ((size_t)tt * 16 + batch) * 2048 + S * 32 + hid;
        float xi = G0[gbase         ] + gl[(0 * 32 + hid) * 17 + batch];
        float xf = G0[gbase +  512  ] + gl[(1 * 32 + hid) * 17 + batch];
        float xg = G0[gbase + 1024  ] + gl[(2 * 32 + hid) * 17 + batch];
        float xo = G0[gbase + 1536  ] + gl[(3 * 32 + hid) * 17 + batch];
        float si = 1.f / (1.f + __expf(-xi));
        float sf = 1.f / (1.f + __expf(-xf));
        float so = 1.f / (1.f + __expf(-xo));
        c_reg = sf * c_reg + si * tanhf(xg);
        float hn = so * tanhf(c_reg);
        Hs[((size_t)tt * 16 + batch) * H_ + S * 32 + hid] = f2bf(hn);
        if (tt == T_ - 1) {
          hcf[(size_t)batch * H_ + S * 32 + hid] = hn;
          hcf[B_ * H_ + (size_t)batch * H_ + S * 32 + hid] = c_reg;
        }
      }
      __syncthreads();               // all stores drained (vmcnt) before release
      if (tid == 0) {
        __threadfence();             // release: write back to IF
        __hip_atomic_fetch_add(&flags[tt], 1, __ATOMIC_RELAXED, __HIP_MEMORY_SCOPE_AGENT);
      }
    }
  } else {
    // ---------------- logits workers (XCDs 1-7; off XCD 0) -----------------
    if (!workers_on) return;
    short* As = (short*)smem;
    short* Bs = (short*)(smem + 16384);
    const int w = bid - (bid >> 3) - 1;              // 0..104
    const int m_in = lane & 15, quad = lane >> 4;
    const int wm = (wave >> 1) * 32, wn = (wave & 1) * 64;   // 8 waves: 4x2
    int prev_gate = -1;
    for (int tile = w; tile < 4000; tile += 105) {
      int ty = tile / 250, tx = tile - ty * 250;
      if (ty != prev_gate) {                         // gate once per t-band
        if (tid == 0) {
          while (__hip_atomic_load(&flags[ty * 8 + 7], __ATOMIC_RELAXED, __HIP_MEMORY_SCOPE_AGENT) < 16)
            __builtin_amdgcn_s_sleep(120);           // ~3.2us poll period
          __threadfence();                           // acquire (local XCD only)
        }
        __syncthreads();
        prev_gate = ty;
      }
      f32x4 acc[2][4] = {};
      const short* Arows = Hs + (size_t)ty * 128 * 512;
      const short* Brows = Wout + (size_t)tx * 128 * 512;
      for (int kt = 0; kt < 512; kt += 64) {
#pragma unroll
        for (int i = 0; i < 2; ++i) {
          int s = i * 512 + tid;
          int r = s >> 3, cs = s & 7, cd = cs ^ (r & 7);
          async_cp16(Arows + ((size_t)r * 512 + kt + cd * 8), &As[s * 8]);
          async_cp16(Brows + ((size_t)r * 512 + kt + cd * 8), &Bs[s * 8]);
        }
        __syncthreads();
#pragma unroll
        for (int kk = 0; kk < 2; ++kk) {
          int c = kk * 4 + quad;
          s16x8 af[2], bfr[4];
#pragma unroll
          for (int i = 0; i < 2; ++i) {
            int ra = wm + i * 16 + m_in;
            af[i] = *(const s16x8*)&As[(ra * 8 + (c ^ (ra & 7))) * 8];
          }
#pragma unroll
          for (int jn = 0; jn < 4; ++jn) {
            int rb = wn + jn * 16 + m_in;
            bfr[jn] = *(const s16x8*)&Bs[(rb * 8 + (c ^ (rb & 7))) * 8];
          }
#pragma unroll
          for (int i = 0; i < 2; ++i)
#pragma unroll
            for (int jn = 0; jn < 4; ++jn)
              acc[i][jn] = MFMA16(af[i], bfr[jn], acc[i][jn], 0, 0, 0);
        }
        __syncthreads();
      }
#pragma unroll
      for (int jn = 0; jn < 4; ++jn) {
        int n = tx * 128 + wn + jn * 16 + m_in;
        float bs = bout[n];
#pragma unroll
        for (int i = 0; i < 2; ++i) {
          int mloc = wm + i * 16 + quad * 4;
          f32x4 a = acc[i][jn];
#pragma unroll
          for (int p = 0; p < 4; ++p) {
            int ml = mloc + p;
            int t = ty * 8 + (ml >> 4), b = ml & 15;
            out[((size_t)b * T_ + t) * (size_t)V_ + n] = a[p] + bs;
          }
        }
      }
    }
  }
}

// ---------------------------------------------------------------------------
extern "C" void kernel_launch(void* const* d_in, const int* in_sizes, int n_in,
                              void* d_out, int out_size, void* d_ws, size_t ws_size,
                              hipStream_t stream) {
  (void)in_sizes; (void)n_in; (void)out_size;
  const float* h0   = (const float*)d_in[1];
  const float* c0   = (const float*)d_in[2];
  const int*   tgt  = (const int*)d_in[3];
  const float* emb  = (const float*)d_in[4];
  const float* Wih  = (const float*)d_in[5];
  const float* Whh  = (const float*)d_in[6];
  const float* bih  = (const float*)d_in[7];
  const float* bhh  = (const float*)d_in[8];
  const float* Wout = (const float*)d_in[9];
  const float* bout = (const float*)d_in[10];
  float* out = (float*)d_out;

  char* ws = (char*)d_ws;
  short* wsWout = (short*)(ws);                 // 32,768,000 B
  short* wsWih  = (short*)(ws + 32768000);      //  2,097,152 B
  short* wsWhh  = (short*)(ws + 34865152);      //  2,097,152 B
  short* wsX    = (short*)(ws + 36962304);      //  2,097,152 B
  short* wsHs   = (short*)(ws + 39059456);      //  2,097,152 B
  int*   flags  = (int*)  (ws + 41156608);      //      4,096 B
  const size_t NEED = 41160704ull + 16777216ull;
  const bool fused = (ws_size >= NEED);         // fused needs G0 in ws
  float* G0 = fused ? (float*)(ws + 41160704) : out;

  cvt_bf16<<<16000, 256, 0, stream>>>(Wout, wsWout, 4096000);
  cvt_bf16<<<1024, 256, 0, stream>>>(Wih, wsWih, 262144);
  cvt_bf16<<<1024, 256, 0, stream>>>(Whh, wsWhh, 262144);
  gather_embed<<<2048, 128, 0, stream>>>(emb, tgt, wsX, flags);
  gemm_bt<<<dim3(16, 16), 256, 0, stream>>>(wsX, wsWih, bih, bhh, G0,
                                            2048, 2048, 512, 2048, 0);
  float* hcf = out + (size_t)B_ * T_ * V_;
  if (fused) {
    rec_logits<<<121, 512, 0, stream>>>(G0, wsWhh, h0, c0, wsHs, wsWout,
                                        bout, flags, out, hcf, 1);
  } else {
    // sequential fallback: recurrence only (G0 in d_out scratch), then GEMM2
    rec_logits<<<121, 512, 0, stream>>>(G0, wsWhh, h0, c0, wsHs, wsWout,
                                        bout, flags, out, hcf, 0);
    gemm_bt<<<dim3(250, 16), 256, 0, stream>>>(wsHs, wsWout, bout, nullptr, out,
                                               2048, 32000, 512, 32000, 1);
  }
}

// Round 13
// 798.010 us; speedup vs baseline: 3.4299x; 1.5202x over previous
//
#include <hip/hip_runtime.h>
#include <hip/hip_bf16.h>
#include <cstdint>

// ---------------------------------------------------------------------------
// Decoder LSTM (teacher-forced), MI355X.
//   1. prep: Wih/Whh fp32->bf16, gather X[t*16+b]=bf16(relu(emb[tok])),
//      zero flags  (single launch)
//   2. gemm_bt: G0 = X @ W_ih^T + b_ih + b_hh  (fp32, t-major rows)
//   3. rec_logits (fused, 121 blocks, 1 block/CU via 156KB LDS):
//      - rec blocks (bid%8==0): R0 fence protocol, PLUS:
//        * runtime XCD check (s_getreg HW_REG_XCC_ID, worker-canary guarded):
//          if all 16 rec blocks share one XCD -> FAST path: plain stores +
//          agent-atomic per-block flags, NO per-step fences (shared-L2
//          visibility; R4 evidence: agent loads are served from local L2).
//          Per-band wbl2+agent flag still published for workers.
//        * G0 register prefetch (removes 4 serial loads from critical path)
//      - workers (bid%8!=0): convert Wout fp32->bf16 first (release-fenced,
//        counter-gated), then logits tiles gated per 8-step band.
//   4. fallback (ws too small): workers off; separate Wout cvt + gemm_bt.
// ---------------------------------------------------------------------------

#define V_ 32000
#define H_ 512
#define B_ 16
#define T_ 128

// hwreg(HW_REG_XCC_ID=20, offset=0, size=4)
#define XCC_HWREG (20 | (3 << 11))

typedef __attribute__((ext_vector_type(8))) short s16x8;
typedef __attribute__((ext_vector_type(4))) float f32x4;

typedef unsigned int __attribute__((address_space(1))) as1_u32;
typedef unsigned int __attribute__((address_space(3))) as3_u32;

#define MFMA16 __builtin_amdgcn_mfma_f32_16x16x32_bf16

__device__ __forceinline__ void async_cp16(const void* g, void* l) {
  __builtin_amdgcn_global_load_lds((const as1_u32*)g, (as3_u32*)l, 16, 0, 0);
}

__device__ __forceinline__ short f2bf(float f) {
  union { float f; unsigned u; } v; v.f = f;
  unsigned r = v.u + 0x7fffu + ((v.u >> 16) & 1u);   // RNE, inputs finite
  return (short)(r >> 16);
}

__device__ __forceinline__ int aload(int* p) {
  return __hip_atomic_load(p, __ATOMIC_RELAXED, __HIP_MEMORY_SCOPE_AGENT);
}
__device__ __forceinline__ void aadd(int* p) {
  __hip_atomic_fetch_add(p, 1, __ATOMIC_RELAXED, __HIP_MEMORY_SCOPE_AGENT);
}

// flags layout (ints): [0..127] step/band flags (agent, fence protocol)
//   [256+S*16] per-block fast step counters  [512+S] rec XCD ids
//   [544+b] worker canary XCD ids  [576] init counter  [577] Wout-cvt counter
// ---------------------------------------------------------------------------
__global__ void cvt_bf16(const float* __restrict__ in, short* __restrict__ out, int n4) {
  int i = blockIdx.x * blockDim.x + threadIdx.x;
  if (i >= n4) return;
  float4 v = ((const float4*)in)[i];
  short4 o;
  o.x = f2bf(v.x); o.y = f2bf(v.y); o.z = f2bf(v.z); o.w = f2bf(v.w);
  ((short4*)out)[i] = o;
}

// Fused prep: grid 2052 x 256.
__global__ void prep(const float* __restrict__ Wih, const float* __restrict__ Whh,
                     short* __restrict__ oIh, short* __restrict__ oHh,
                     const float* __restrict__ emb, const int* __restrict__ tgt,
                     short* __restrict__ X, int* __restrict__ flags) {
  int bid = blockIdx.x, tid = threadIdx.x;
  if (bid < 1024) {                       // Wih + Whh cvt (262144 float4 each)
    int i = bid * 256 + tid;
    float4 a = ((const float4*)Wih)[i];
    short4 o;
    o.x = f2bf(a.x); o.y = f2bf(a.y); o.z = f2bf(a.z); o.w = f2bf(a.w);
    ((short4*)oIh)[i] = o;
    float4 b = ((const float4*)Whh)[i];
    short4 p;
    p.x = f2bf(b.x); p.y = f2bf(b.y); p.z = f2bf(b.z); p.w = f2bf(b.w);
    ((short4*)oHh)[i] = p;
  } else if (bid < 2048) {                // gather: 2 rows per block, t-major X
    int m = (bid - 1024) * 2 + (tid >> 7);
    int b = m >> 7, t = m & 127;
    int tok = (t == 0) ? 1 : tgt[b * T_ + t - 1];     // BOS = 1
    int k = (tid & 127) * 4;
    float4 v = *(const float4*)&emb[(size_t)tok * H_ + k];
    short4 o;
    o.x = f2bf(fmaxf(v.x, 0.f)); o.y = f2bf(fmaxf(v.y, 0.f));
    o.z = f2bf(fmaxf(v.z, 0.f)); o.w = f2bf(fmaxf(v.w, 0.f));
    *(short4*)&X[((size_t)t * 16 + b) * H_ + k] = o;
  } else {                                // zero 1024 flag ints
    flags[(bid - 2048) * 256 + tid] = 0;
  }
}

// ---------------------------------------------------------------------------
// C = A(MxK bf16) @ B(NxK bf16)^T + bias ; 128x128 tile, BK=64, 4 waves.
__global__ __launch_bounds__(256, 2) void gemm_bt(
    const short* __restrict__ A, const short* __restrict__ B,
    const float* __restrict__ bias0, const float* __restrict__ bias1,
    float* __restrict__ out, int M, int N, int K, int ldo, int tmajor)
{
  __shared__ short As[1024 * 8];
  __shared__ short Bs[1024 * 8];
  const int tid = threadIdx.x;
  const int wave = tid >> 6, lane = tid & 63;
  const int row0 = blockIdx.y * 128, col0 = blockIdx.x * 128;
  const int m_in = lane & 15, quad = lane >> 4;
  const int wm = (wave >> 1) * 64, wn = (wave & 1) * 64;
  f32x4 acc[4][4] = {};
  for (int kt = 0; kt < K; kt += 64) {
    for (int i = 0; i < 4; ++i) {
      int s = (i * 4 + wave) * 64 + lane;
      int r = s >> 3, cs = s & 7, cd = cs ^ (r & 7);
      async_cp16(A + ((size_t)(row0 + r) * K + kt + cd * 8), &As[s * 8]);
      async_cp16(B + ((size_t)(col0 + r) * K + kt + cd * 8), &Bs[s * 8]);
    }
    __syncthreads();
    for (int kk = 0; kk < 2; ++kk) {
      s16x8 af[4], bfr[4];
      int c = kk * 4 + quad;
      for (int i = 0; i < 4; ++i) {
        int ra = wm + i * 16 + m_in;
        af[i] = *(const s16x8*)&As[(ra * 8 + (c ^ (ra & 7))) * 8];
        int rb = wn + i * 16 + m_in;
        bfr[i] = *(const s16x8*)&Bs[(rb * 8 + (c ^ (rb & 7))) * 8];
      }
      for (int i = 0; i < 4; ++i)
        for (int j = 0; j < 4; ++j)
          acc[i][j] = MFMA16(af[i], bfr[j], acc[i][j], 0, 0, 0);
    }
    __syncthreads();
  }
  for (int j = 0; j < 4; ++j) {
    int n = col0 + wn + j * 16 + m_in;
    float bs = bias0[n] + (bias1 ? bias1[n] : 0.f);
    for (int i = 0; i < 4; ++i) {
      int mrow = row0 + wm + i * 16 + quad * 4;
      f32x4 a = acc[i][j];
      for (int p = 0; p < 4; ++p) {
        int mr = mrow + p;
        int orow = tmajor ? ((mr & 15) * T_ + (mr >> 4)) : mr;
        out[(size_t)orow * ldo + n] = a[p] + bs;
      }
    }
  }
}

// ---------------------------------------------------------------------------
__global__ __launch_bounds__(512, 1) void rec_logits(
    const float* __restrict__ G0,    // [2048][2048] fp32, rows t-major
    const short* __restrict__ Whh,   // [2048][512] bf16
    const float* __restrict__ h0, const float* __restrict__ c0,
    short* __restrict__ Hs,          // [2048][512] bf16, rows t-major
    const short* __restrict__ Wout,  // [32000][512] bf16 (= WoutB)
    const float* __restrict__ bout,
    int* flags,
    float* __restrict__ out,         // logits, row b*T+t
    float* __restrict__ hcf,         // hf[B*H] then cf[B*H]
    const float* __restrict__ WoutF, // fp32 Wout (workers convert); null->skip
    short* __restrict__ WoutB,
    int workers_on)
{
  __shared__ char smem[156160];
  const int bid = blockIdx.x;
  const int tid = threadIdx.x, wave = tid >> 6, lane = tid & 63;
  const bool isrec = ((bid & 7) == 0);

  // ---- publish XCD id (rec blocks + worker canaries bid 1..7) ----
  if (tid == 0 && (isrec || bid < 8)) {
    int xcc = __builtin_amdgcn_s_getreg(XCC_HWREG) & 15;
    flags[isrec ? (512 + (bid >> 3)) : (544 + bid)] = xcc;
    __threadfence();
    aadd(&flags[576]);
  }

  if (isrec) {
    // ------------------------- recurrence -------------------------
    short* Wl = (short*)smem;                       // 128 rows x 64 chunks x 16B
    short* hl = (short*)(smem + 131072);            // 16 rows x 64 chunks x 16B
    float* gl = (float*)(smem + 147456);            // [128][17] fp32
    const int S = bid >> 3;
    const int nin = lane & 15, quad = lane >> 4;

    // decide FAST (same-XCD) vs SLOW (fence protocol)
    if (tid == 0) {
      while (aload(&flags[576]) < 23) {}
      __threadfence();                              // acquire: fresh ids
      int id0 = flags[512], same = 1, diff = 0;
      for (int s = 1; s < 16; ++s) same &= (flags[512 + s] == id0);
      for (int b = 1; b < 8; ++b) diff |= (flags[544 + b] != id0);
      *(int*)smem = (same && diff) ? 1 : 0;
    }
    __syncthreads();
    const int FAST = *(int*)smem;
    __syncthreads();                                // before Wl overwrites smem[0]

    // Stage W slice. Local row r -> global unit (r/32)*512 + S*32 + (r%32).
    for (int i = tid; i < 8192; i += 512) {
      int r = i >> 6, cs = i & 63, cd = cs ^ (r & 7);
      int u = (r >> 5) * 512 + S * 32 + (r & 31);
      *(int4*)&Wl[i * 8] = *(const int4*)&Whh[(size_t)u * H_ + cd * 8];
    }
    const int batch = tid >> 5, hid = tid & 31;
    float c_reg = c0[batch * H_ + S * 32 + hid];
    // G0 prefetch for tt=0 (row = 0*16 + batch)
    size_t gb = (size_t)batch * 2048 + S * 32 + hid;
    float gx0 = G0[gb], gx1 = G0[gb + 512], gx2 = G0[gb + 1024], gx3 = G0[gb + 1536];
    __syncthreads();

    for (int tt = 0; tt < T_; ++tt) {
      if (tt > 0) {
        if (FAST) {                                 // no fences: shared-L2 data
          if (wave == 0) {
            while (true) {
              int f = 0x7fffffff;
              if (lane < 16) f = aload(&flags[256 + lane * 16]);
              if (__ballot(f >= tt) == ~0ull) break;
              __builtin_amdgcn_s_sleep(1);
            }
          }
          __syncthreads();
        } else {
          if (tid == 0) {
            while (aload(&flags[tt - 1]) < 16) {}
            __threadfence();                        // acquire
          }
          __syncthreads();
        }
      }
      // Stage h (16 batches x 512) into hl, swizzled.
      for (int i = tid; i < 1024; i += 512) {
        int m = i >> 6, cs = i & 63, cd = cs ^ (m & 7);
        if (tt == 0) {
          const float* hp = &h0[m * H_ + cd * 8];
          float4 v0 = *(const float4*)hp, v1 = *(const float4*)(hp + 4);
          s16x8 o;
          o[0] = f2bf(v0.x); o[1] = f2bf(v0.y); o[2] = f2bf(v0.z); o[3] = f2bf(v0.w);
          o[4] = f2bf(v1.x); o[5] = f2bf(v1.y); o[6] = f2bf(v1.z); o[7] = f2bf(v1.w);
          *(s16x8*)&hl[i * 8] = o;
        } else {
          *(int4*)&hl[i * 8] = *(const int4*)&Hs[((size_t)(tt - 1) * 16 + m) * H_ + cd * 8];
        }
      }
      __syncthreads();
      // MFMA: wave w computes units [w*16, w*16+16) x 16 batches over K=512.
      {
        f32x4 acc = {};
        int r = wave * 16 + nin;
        for (int ks = 0; ks < 16; ++ks) {
          int c = ks * 4 + quad;
          s16x8 af = *(const s16x8*)&hl[(nin * 64 + (c ^ (nin & 7))) * 8];
          s16x8 bf = *(const s16x8*)&Wl[(r * 64 + (c ^ (r & 7))) * 8];
          acc = MFMA16(af, bf, acc, 0, 0, 0);
        }
        int u = wave * 16 + nin;
        for (int p = 0; p < 4; ++p)
          gl[u * 17 + quad * 4 + p] = acc[p];
      }
      __syncthreads();
      // Pointwise gates (fp32) with PREFETCHED G0.
      {
        float xi = gx0 + gl[(0 * 32 + hid) * 17 + batch];
        float xf = gx1 + gl[(1 * 32 + hid) * 17 + batch];
        float xg = gx2 + gl[(2 * 32 + hid) * 17 + batch];
        float xo = gx3 + gl[(3 * 32 + hid) * 17 + batch];
        float si = 1.f / (1.f + __expf(-xi));
        float sf = 1.f / (1.f + __expf(-xf));
        float so = 1.f / (1.f + __expf(-xo));
        c_reg = sf * c_reg + si * tanhf(xg);
        float hn = so * tanhf(c_reg);
        Hs[((size_t)tt * 16 + batch) * H_ + S * 32 + hid] = f2bf(hn);
        if (tt == T_ - 1) {
          hcf[(size_t)batch * H_ + S * 32 + hid] = hn;
          hcf[B_ * H_ + (size_t)batch * H_ + S * 32 + hid] = c_reg;
        }
      }
      __syncthreads();               // Hs stores drained (vmcnt) -> in L2
      if (tid == 0) {
        if (FAST) {
          aadd(&flags[256 + S * 16]);              // rec peers: shared-L2 data
          if ((tt & 7) == 7) {
            __threadfence();                       // wbl2: band Hs -> IF
            aadd(&flags[tt]);                      // workers' band gate
          }
        } else {
          __threadfence();                         // release
          aadd(&flags[tt]);
        }
      }
      if (tt < T_ - 1) {                           // prefetch next G0 row;
        size_t g2 = ((size_t)(tt + 1) * 16 + batch) * 2048 + S * 32 + hid;
        gx0 = G0[g2]; gx1 = G0[g2 + 512];          // overlaps next spin
        gx2 = G0[g2 + 1024]; gx3 = G0[g2 + 1536];
      }
    }
  } else {
    // ------------------------- logits workers -------------------------
    if (!workers_on) return;
    const int w = bid - (bid >> 3) - 1;            // 0..104
    if (WoutF) {                                   // convert Wout share
      for (int i = w * 512 + tid; i < 4096000; i += 105 * 512) {
        float4 a = ((const float4*)WoutF)[i];
        short4 o;
        o.x = f2bf(a.x); o.y = f2bf(a.y); o.z = f2bf(a.z); o.w = f2bf(a.w);
        ((short4*)WoutB)[i] = o;
      }
      __syncthreads();                             // stores drained -> L2
      if (tid == 0) {
        __threadfence();                           // release share to IF
        aadd(&flags[577]);
      }
    }
    short* As = (short*)smem;
    short* Bs = (short*)(smem + 16384);
    const int m_in = lane & 15, quad = lane >> 4;
    const int wm = (wave >> 1) * 32, wn = (wave & 1) * 64;
    int prev_gate = -1;
    for (int tile = w; tile < 4000; tile += 105) {
      int ty = tile / 250, tx = tile - ty * 250;
      if (ty != prev_gate) {
        if (tid == 0) {
          if (prev_gate < 0 && WoutF)
            while (aload(&flags[577]) < 105) __builtin_amdgcn_s_sleep(120);
          while (aload(&flags[ty * 8 + 7]) < 16) __builtin_amdgcn_s_sleep(120);
          __threadfence();                         // acquire
        }
        __syncthreads();
        prev_gate = ty;
      }
      f32x4 acc[2][4] = {};
      const short* Arows = Hs + (size_t)ty * 128 * 512;
      const short* Brows = Wout + (size_t)tx * 128 * 512;
      for (int kt = 0; kt < 512; kt += 64) {
#pragma unroll
        for (int i = 0; i < 2; ++i) {
          int s = i * 512 + tid;
          int r = s >> 3, cs = s & 7, cd = cs ^ (r & 7);
          async_cp16(Arows + ((size_t)r * 512 + kt + cd * 8), &As[s * 8]);
          async_cp16(Brows + ((size_t)r * 512 + kt + cd * 8), &Bs[s * 8]);
        }
        __syncthreads();
#pragma unroll
        for (int kk = 0; kk < 2; ++kk) {
          int c = kk * 4 + quad;
          s16x8 af[2], bfr[4];
#pragma unroll
          for (int i = 0; i < 2; ++i) {
            int ra = wm + i * 16 + m_in;
            af[i] = *(const s16x8*)&As[(ra * 8 + (c ^ (ra & 7))) * 8];
          }
#pragma unroll
          for (int jn = 0; jn < 4; ++jn) {
            int rb = wn + jn * 16 + m_in;
            bfr[jn] = *(const s16x8*)&Bs[(rb * 8 + (c ^ (rb & 7))) * 8];
          }
#pragma unroll
          for (int i = 0; i < 2; ++i)
#pragma unroll
            for (int jn = 0; jn < 4; ++jn)
              acc[i][jn] = MFMA16(af[i], bfr[jn], acc[i][jn], 0, 0, 0);
        }
        __syncthreads();
      }
#pragma unroll
      for (int jn = 0; jn < 4; ++jn) {
        int n = tx * 128 + wn + jn * 16 + m_in;
        float bs = bout[n];
#pragma unroll
        for (int i = 0; i < 2; ++i) {
          int mloc = wm + i * 16 + quad * 4;
          f32x4 a = acc[i][jn];
#pragma unroll
          for (int p = 0; p < 4; ++p) {
            int ml = mloc + p;
            int t = ty * 8 + (ml >> 4), b = ml & 15;
            out[((size_t)b * T_ + t) * (size_t)V_ + n] = a[p] + bs;
          }
        }
      }
    }
  }
}

// ---------------------------------------------------------------------------
extern "C" void kernel_launch(void* const* d_in, const int* in_sizes, int n_in,
                              void* d_out, int out_size, void* d_ws, size_t ws_size,
                              hipStream_t stream) {
  (void)in_sizes; (void)n_in; (void)out_size;
  const float* h0   = (const float*)d_in[1];
  const float* c0   = (const float*)d_in[2];
  const int*   tgt  = (const int*)d_in[3];
  const float* emb  = (const float*)d_in[4];
  const float* Wih  = (const float*)d_in[5];
  const float* Whh  = (const float*)d_in[6];
  const float* bih  = (const float*)d_in[7];
  const float* bhh  = (const float*)d_in[8];
  const float* Wout = (const float*)d_in[9];
  const float* bout = (const float*)d_in[10];
  float* out = (float*)d_out;

  char* ws = (char*)d_ws;
  short* wsWout = (short*)(ws);                 // 32,768,000 B
  short* wsWih  = (short*)(ws + 32768000);      //  2,097,152 B
  short* wsWhh  = (short*)(ws + 34865152);      //  2,097,152 B
  short* wsX    = (short*)(ws + 36962304);      //  2,097,152 B
  short* wsHs   = (short*)(ws + 39059456);      //  2,097,152 B
  int*   flags  = (int*)  (ws + 41156608);      //      4,096 B
  const size_t NEED = 41160704ull + 16777216ull;
  const bool fused = (ws_size >= NEED);         // fused needs G0 in ws
  float* G0 = fused ? (float*)(ws + 41160704) : out;

  prep<<<2052, 256, 0, stream>>>(Wih, Whh, wsWih, wsWhh, emb, tgt, wsX, flags);
  gemm_bt<<<dim3(16, 16), 256, 0, stream>>>(wsX, wsWih, bih, bhh, G0,
                                            2048, 2048, 512, 2048, 0);
  float* hcf = out + (size_t)B_ * T_ * V_;
  if (fused) {
    rec_logits<<<121, 512, 0, stream>>>(G0, wsWhh, h0, c0, wsHs, wsWout,
                                        bout, flags, out, hcf,
                                        Wout, wsWout, 1);
  } else {
    cvt_bf16<<<16000, 256, 0, stream>>>(Wout, wsWout, 4096000);
    rec_logits<<<121, 512, 0, stream>>>(G0, wsWhh, h0, c0, wsHs, wsWout,
                                        bout, flags, out, hcf,
                                        nullptr, nullptr, 0);
    gemm_bt<<<dim3(250, 16), 256, 0, stream>>>(wsHs, wsWout, bout, nullptr, out,
                                               2048, 32000, 512, 32000, 1);
  }
}